// Round 4
// baseline (391.491 us; speedup 1.0000x reference)
//
#include <hip/hip_runtime.h>
#include <hip/hip_cooperative_groups.h>
#include <math.h>

// Problem: N=262144, D=128, C=1024. fp32 embeddings, int32/int64 labels.
// Identity: per_class = (count - ||sum_{i in c} norm(emb_i)||) / count.
// 3 dispatches: memset(16KB) + cooperative prep (hist+scan+scatter+inv_norm)
// + class_sum gather (short chain: idx -> row+inv -> FMA; depth-2 pipeline).
#define NUM_CLASSES 1024
#define PREP_BLOCKS 512
#define PREP_THREADS 512

namespace cg = cooperative_groups;

__device__ __forceinline__ int detect_mode32(const int* __restrict__ l) {
    // uniform scalar loads; 1 -> labels are int32, 0 -> int64 (read low words)
    return (l[1] | l[3] | l[5] | l[7] | l[9] | l[11] | l[13] | l[15]) != 0;
}

__device__ __forceinline__ int get_label(const int* __restrict__ l, int i, int mode32) {
    return l[mode32 ? i : (i << 1)] & (NUM_CLASSES - 1);
}

__device__ __forceinline__ float sumsq8(const float4 a, const float4 b) {
    return a.x*a.x + a.y*a.y + a.z*a.z + a.w*a.w
         + b.x*b.x + b.y*b.y + b.z*b.z + b.w*b.w;
}

__device__ __forceinline__ float red16(float sq) {
    sq += __shfl_xor(sq, 1, 64);
    sq += __shfl_xor(sq, 2, 64);
    sq += __shfl_xor(sq, 4, 64);
    sq += __shfl_xor(sq, 8, 64);
    return sq;
}

// ---------------- Cooperative prep kernel ----------------
// P1: per-block LDS hist -> global counts (atomics; counts pre-zeroed) and
//     coalesced inv_norm streaming pass (16 lanes/row, 4 rows in flight).
// sync. P2: block 0 scans counts -> offsets, cursor. sync.
// P3: per-block scatter: one global atomicAdd per (block,class) for the base,
//     LDS cursors for intra-block placement.
__global__ __launch_bounds__(PREP_THREADS, 8) void prep_kernel(
        const float* __restrict__ emb, const int* __restrict__ labels, int n,
        int* __restrict__ counts, int* __restrict__ offsets,
        int* __restrict__ cursor, float* __restrict__ inv_norm,
        int* __restrict__ sorted) {
    cg::grid_group grid = cg::this_grid();
    __shared__ int h[NUM_CLASSES];       // block hist (persists to P3)
    __shared__ int cur[NUM_CLASSES];     // block scatter cursors
    __shared__ int tmp[PREP_THREADS];    // block-0 scan scratch

    const int mode32 = detect_mode32(labels);
    const int nb  = gridDim.x;
    const int spb = (n + nb - 1) / nb;
    const int s0  = blockIdx.x * spb;
    const int s1  = min(n, s0 + spb);

    // ---- P1a: block histogram + global flush
    for (int c = threadIdx.x; c < NUM_CLASSES; c += PREP_THREADS) h[c] = 0;
    __syncthreads();
    for (int i = s0 + threadIdx.x; i < s1; i += PREP_THREADS)
        atomicAdd(&h[get_label(labels, i, mode32)], 1);
    __syncthreads();
    for (int c = threadIdx.x; c < NUM_CLASSES; c += PREP_THREADS) {
        int v = h[c];
        if (v) atomicAdd(&counts[c], v);
    }

    // ---- P1b: inv_norm (coalesced stream, 16 lanes/row, unroll 4)
    if (s0 < n) {
        const int wave = threadIdx.x >> 6, lane = threadIdx.x & 63;
        const int g = lane >> 4, sub = lane & 15;
        const int grp = wave * 4 + g;        // 0..31
        const float4* emb4 = (const float4*)emb;
        const int nrows = s1 - s0;
        const int quads = nrows >> 7;        // full 128-row stripes
        for (int q = 0; q < quads; ++q) {
            const int base = s0 + (q << 7) + grp;
            const float4* p0 = emb4 + (size_t)(base     ) * 32;
            const float4* p1 = emb4 + (size_t)(base + 32) * 32;
            const float4* p2 = emb4 + (size_t)(base + 64) * 32;
            const float4* p3 = emb4 + (size_t)(base + 96) * 32;
            float4 a0 = p0[sub], a1 = p0[sub + 16];
            float4 b0 = p1[sub], b1 = p1[sub + 16];
            float4 c0 = p2[sub], c1 = p2[sub + 16];
            float4 d0 = p3[sub], d1 = p3[sub + 16];
            float sa = red16(sumsq8(a0, a1));
            float sb = red16(sumsq8(b0, b1));
            float sc = red16(sumsq8(c0, c1));
            float sd = red16(sumsq8(d0, d1));
            if (sub == 0) {
                inv_norm[base     ] = 1.0f / fmaxf(sqrtf(sa), 1e-12f);
                inv_norm[base + 32] = 1.0f / fmaxf(sqrtf(sb), 1e-12f);
                inv_norm[base + 64] = 1.0f / fmaxf(sqrtf(sc), 1e-12f);
                inv_norm[base + 96] = 1.0f / fmaxf(sqrtf(sd), 1e-12f);
            }
        }
        const int done = quads << 7;
        const int rem  = nrows - done;
        const int kmax = (rem + 31) >> 5;    // group-uniform trip count
        for (int k = 0; k < kmax; ++k) {
            int row = s0 + done + (k << 5) + grp;
            bool valid = row < s1;
            int rr = valid ? row : s0;       // clamped safe load
            const float4* p = emb4 + (size_t)rr * 32;
            float4 a0 = p[sub], a1 = p[sub + 16];
            float sa = red16(sumsq8(a0, a1));
            if (valid && sub == 0)
                inv_norm[row] = 1.0f / fmaxf(sqrtf(sa), 1e-12f);
        }
    }

    grid.sync();

    // ---- P2: block 0 exclusive scan of counts -> offsets, cursor
    if (blockIdx.x == 0) {
        const int t = threadIdx.x;           // 512 threads, 2 classes each
        int v0 = counts[2 * t];
        int v1 = counts[2 * t + 1];
        int s = v0 + v1;
        tmp[t] = s;
        __syncthreads();
        for (int off = 1; off < PREP_THREADS; off <<= 1) {
            int add = (t >= off) ? tmp[t - off] : 0;
            __syncthreads();
            tmp[t] += add;
            __syncthreads();
        }
        int excl = tmp[t] - s;
        offsets[2 * t]     = excl;
        offsets[2 * t + 1] = excl + v0;
        cursor[2 * t]      = excl;
        cursor[2 * t + 1]  = excl + v0;
    }

    grid.sync();

    // ---- P3: scatter (global atomic base per (block,class), LDS cursors)
    for (int c = threadIdx.x; c < NUM_CLASSES; c += PREP_THREADS) {
        int v = h[c];
        cur[c] = v ? atomicAdd(&cursor[c], v) : 0;
    }
    __syncthreads();
    for (int i = s0 + threadIdx.x; i < s1; i += PREP_THREADS) {
        int pos = atomicAdd(&cur[get_label(labels, i, mode32)], 1);
        sorted[pos] = i;
    }
}

// ---------------- class_sum: gather + weighted accumulate + loss ----------------
// One block (8 waves) per class; 16 lanes/row, 32 row-groups. inv_norm is
// precomputed, so the loop chain is idx -> row+inv -> FMA (no shfl/rsqrt).
// Branchless depth-2 pipeline over 2-row stages (4 rows outstanding),
// clamped indices (row 0 with weight 0) -> uniform trip count per block.
#define WPB 8
__global__ __launch_bounds__(512, 4) void class_sum_kernel(
        const float* __restrict__ emb,
        const int* __restrict__ sorted,
        const int* __restrict__ offsets,
        const int* __restrict__ counts,
        const float* __restrict__ inv_norm,
        float* __restrict__ accum,          // [0]=loss_sum, [1]=n_valid
        int* __restrict__ ticket,
        float* __restrict__ out) {
    const int c     = blockIdx.x;
    const int start = offsets[c];
    const int count = counts[c];
    const int wave  = threadIdx.x >> 6;
    const int lane  = threadIdx.x & 63;
    const int g     = lane >> 4;
    const int sub   = lane & 15;
    const int r0    = wave * 4 + g;         // 0..31

    const float4* emb4 = (const float4*)emb;
    const int* sp = sorted + start;

    float4 aLo = make_float4(0.f, 0.f, 0.f, 0.f);
    float4 aHi = make_float4(0.f, 0.f, 0.f, 0.f);
    const int FULL = count >> 5;            // uniform rows per group

    // stage A (t=0,1) loads
    int iA0 = (0 < FULL) ? sp[r0]      : 0;
    int iA1 = (1 < FULL) ? sp[r0 + 32] : 0;
    const float4* pA0 = emb4 + (size_t)iA0 * 32;
    const float4* pA1 = emb4 + (size_t)iA1 * 32;
    float4 a00 = pA0[sub], a01 = pA0[sub + 16];
    float4 a10 = pA1[sub], a11 = pA1[sub + 16];
    float  wA0 = (0 < FULL) ? inv_norm[iA0] : 0.0f;
    float  wA1 = (1 < FULL) ? inv_norm[iA1] : 0.0f;
    // stage B indices (t=2,3)
    int iB0 = (2 < FULL) ? sp[r0 + 64] : 0;
    int iB1 = (3 < FULL) ? sp[r0 + 96] : 0;

    const int STAGES = (FULL + 1) >> 1;     // uniform per block
    for (int s = 0; s < STAGES; ++s) {
        const int tn = 2 * s + 2;           // next stage's first t
        // issue next stage's row+inv loads (indices already resident)
        const float4* pB0 = emb4 + (size_t)iB0 * 32;
        const float4* pB1 = emb4 + (size_t)iB1 * 32;
        float4 b00 = pB0[sub], b01 = pB0[sub + 16];
        float4 b10 = pB1[sub], b11 = pB1[sub + 16];
        float  wB0 = (tn     < FULL) ? inv_norm[iB0] : 0.0f;
        float  wB1 = (tn + 1 < FULL) ? inv_norm[iB1] : 0.0f;
        // prefetch indices for stage s+2
        int iC0 = (tn + 2 < FULL) ? sp[r0 + 32 * (tn + 2)] : 0;
        int iC1 = (tn + 3 < FULL) ? sp[r0 + 32 * (tn + 3)] : 0;
        // consume current stage (t ascending; deterministic order)
        aLo.x += a00.x * wA0; aLo.y += a00.y * wA0; aLo.z += a00.z * wA0; aLo.w += a00.w * wA0;
        aHi.x += a01.x * wA0; aHi.y += a01.y * wA0; aHi.z += a01.z * wA0; aHi.w += a01.w * wA0;
        aLo.x += a10.x * wA1; aLo.y += a10.y * wA1; aLo.z += a10.z * wA1; aLo.w += a10.w * wA1;
        aHi.x += a11.x * wA1; aHi.y += a11.y * wA1; aHi.z += a11.z * wA1; aHi.w += a11.w * wA1;
        // rotate
        a00 = b00; a01 = b01; a10 = b10; a11 = b11;
        wA0 = wB0; wA1 = wB1; iB0 = iC0; iB1 = iC1;
    }
    {   // masked tail row
        const int r = r0 + 32 * FULL;
        if (r < count) {
            const int idx = sp[r];
            const float4* p = emb4 + (size_t)idx * 32;
            float4 a0 = p[sub], a1 = p[sub + 16];
            float w = inv_norm[idx];
            aLo.x += a0.x * w; aLo.y += a0.y * w; aLo.z += a0.z * w; aLo.w += a0.w * w;
            aHi.x += a1.x * w; aHi.y += a1.y * w; aHi.z += a1.z * w; aHi.w += a1.w * w;
        }
    }

    // Reduce 32 partial vectors (8 waves x 4 groups) of 128 dims.
    __shared__ float s[WPB * 4][16][8];     // 16 KB
    {
        float* dst = s[wave * 4 + g][sub];
        dst[0] = aLo.x; dst[1] = aLo.y; dst[2] = aLo.z; dst[3] = aLo.w;
        dst[4] = aHi.x; dst[5] = aHi.y; dst[6] = aHi.z; dst[7] = aHi.w;
    }
    __syncthreads();

    __shared__ float red[128];
    if (threadIdx.x < 128) {
        const int d  = threadIdx.x;
        const int dd = d & 63;
        const int sb = dd >> 2;
        const int j  = (d >> 6) * 4 + (dd & 3);
        float tt = 0.0f;
        #pragma unroll
        for (int k = 0; k < WPB * 4; k++) tt += s[k][sb][j];
        red[d] = tt * tt;
    }
    __syncthreads();
    if (threadIdx.x < 64) {
        float x = red[threadIdx.x] + red[threadIdx.x + 64];
        #pragma unroll
        for (int off = 32; off; off >>= 1) x += __shfl_xor(x, off, 64);
        if (threadIdx.x == 0) {
            if (count >= 2) {
                float nrm = sqrtf(x);                   // = sum over class of sim
                float per_class = ((float)count - nrm) / (float)count;
                atomicAdd(&accum[0], per_class);
                atomicAdd(&accum[1], 1.0f);
            }
            __threadfence();
            int old = atomicAdd(ticket, 1);
            if (old == NUM_CLASSES - 1) {
                float ls = atomicAdd(&accum[0], 0.0f);  // device-scope reads
                float nv = atomicAdd(&accum[1], 0.0f);
                out[0] = (nv > 0.0f) ? (ls / nv) : 0.0f;
            }
        }
    }
}

extern "C" void kernel_launch(void* const* d_in, const int* in_sizes, int n_in,
                              void* d_out, int out_size, void* d_ws, size_t ws_size,
                              hipStream_t stream) {
    const float* emb  = (const float*)d_in[0];   // fp32, N x 128
    const int* labels = (const int*)d_in[1];     // int32 (int64 handled inline)
    int n = in_sizes[1];                         // 262144 samples

    // Workspace layout (~2.1 MB)
    char* ws = (char*)d_ws;
    int*   counts   = (int*)(ws + 0);            // 1024 ints
    int*   offsets  = (int*)(ws + 4096);         // 1024 ints
    int*   cursor   = (int*)(ws + 8192);         // 1024 ints
    float* accum    = (float*)(ws + 12288);      // 2 floats
    int*   ticket   = (int*)(ws + 12296);        // 1 int
    float* inv_norm = (float*)(ws + 16384);      // n floats (1 MB)
    int*   sorted   = (int*)(ws + 16384 + (size_t)n * 4);  // n ints (1 MB)

    hipMemsetAsync(ws, 0, 16384, stream);        // counts/cursor/accum/ticket

    void* args[] = { (void*)&emb, (void*)&labels, (void*)&n,
                     (void*)&counts, (void*)&offsets, (void*)&cursor,
                     (void*)&inv_norm, (void*)&sorted };
    hipLaunchCooperativeKernel((void*)prep_kernel, dim3(PREP_BLOCKS),
                               dim3(PREP_THREADS), args, 0, stream);

    class_sum_kernel<<<NUM_CLASSES, 512, 0, stream>>>(emb, sorted, offsets,
                                                      counts, inv_norm, accum,
                                                      ticket, (float*)d_out);
}